// Round 1
// baseline (515.436 us; speedup 1.0000x reference)
//
#include <hip/hip_runtime.h>

typedef unsigned short u16;
typedef unsigned int   u32;
typedef __attribute__((ext_vector_type(8))) short short8;   // 8 bf16 (4 VGPR)
typedef __attribute__((ext_vector_type(4))) float f32x4;

#define DEV static __device__ __forceinline__

DEV u16 f2bf(float f){                       // f32 -> bf16 RNE
  union { float f; u32 u; } v; v.f = f;
  u32 u = v.u;
  u += 0x7fffu + ((u >> 16) & 1u);
  return (u16)(u >> 16);
}
DEV float sigmoidf_(float x){ return 1.f / (1.f + __expf(-x)); }
DEV float tanh_fast(float x){ float e = __expf(2.f * x); return 1.f - 2.f / (e + 1.f); }

DEV void gload16(const void* g, void* l){    // async global->LDS, 16B/lane, dest = uniform base + lane*16
  __builtin_amdgcn_global_load_lds(
      (const __attribute__((address_space(1))) void*)g,
      (__attribute__((address_space(3))) void*)l, 16, 0, 0);
}
DEV f32x4 mfma16(short8 a, short8 b, f32x4 c){
  return __builtin_amdgcn_mfma_f32_16x16x32_bf16(a, b, c, 0, 0, 0);
}

// ---------------------------------------------------------------------------
// transpose + f32->bf16: src (K x N) f32  ->  dst (N x K) bf16
// grid (K/64, N/64), block 256
__global__ __launch_bounds__(256) void k_transpose_cvt(
    const float* __restrict__ src, u16* __restrict__ dst, int K, int N){
  __shared__ u16 t[64][72];
  int k0 = blockIdx.x << 6, n0 = blockIdx.y << 6;
  int tid = threadIdx.x;
  int c = tid & 63;
  for (int r = tid >> 6; r < 64; r += 4)
    t[r][c] = f2bf(src[(size_t)(k0 + r) * N + n0 + c]);
  __syncthreads();
  int n = tid >> 2, c0 = (tid & 3) << 4;
  union { u16 s[16]; uint4 q[2]; } pk;
#pragma unroll
  for (int i = 0; i < 16; i++) pk.s[i] = t[c0 + i][n];
  uint4* o = (uint4*)(dst + (size_t)(n0 + n) * K + k0 + c0);
  o[0] = pk.q[0]; o[1] = pk.q[1];
}

// ---------------------------------------------------------------------------
// q[b,u] = prevState[b,:] @ Ww[:,u] + bw[u] + bu[u]   (f32, exact bias path)
// grid 128 (8 b each), block 512 (tid = u)
__global__ __launch_bounds__(512) void k_q(
    const float* __restrict__ ps, const float* __restrict__ Ww,
    const float* __restrict__ bw, const float* __restrict__ bu,
    float* __restrict__ q){
  __shared__ float psl[8][512];
  int b0 = blockIdx.x << 3;
  int tid = threadIdx.x;
#pragma unroll
  for (int i = 0; i < 8; i++) psl[i][tid] = ps[(size_t)(b0 + i) * 512 + tid];
  __syncthreads();
  float acc[8] = {0,0,0,0,0,0,0,0};
  for (int j = 0; j < 512; j++){
    float w = Ww[(size_t)j * 512 + tid];
#pragma unroll
    for (int i = 0; i < 8; i++) acc[i] = fmaf(psl[i][j], w, acc[i]);
  }
  float bias = bw[tid] + bu[tid];
#pragma unroll
  for (int i = 0; i < 8; i++) q[(size_t)(b0 + i) * 512 + tid] = acc[i] + bias;
}

// ---------------------------------------------------------------------------
// x_bf16[b, 2048+e] = bf16(emb[tokens[b], e]);  grid 1024, block 256
__global__ __launch_bounds__(256) void k_gather(
    const int* __restrict__ tok, const float* __restrict__ emb, u16* __restrict__ xbf){
  int b = blockIdx.x, e = threadIdx.x;
  int t = tok[b];
  xbf[(size_t)b * 2304 + 2048 + e] = f2bf(emb[(size_t)t * 256 + e]);
}

// ---------------------------------------------------------------------------
// bn scale/offset precompute: y = acc*bns[u] + bno[u]
__global__ __launch_bounds__(512) void k_bnprep(
    const float* __restrict__ gamma, const float* __restrict__ beta,
    const float* __restrict__ mmean, const float* __restrict__ mvar,
    const float* __restrict__ b1, float* __restrict__ bns, float* __restrict__ bno){
  int u = threadIdx.x;
  float sc = gamma[u] * rsqrtf(mvar[u] + 1e-3f);
  bns[u] = sc;
  bno[u] = (b1[u] - mmean[u]) * sc + beta[u];
}

// ---------------------------------------------------------------------------
// fused attention: per block b:
//   S1(64x512) = FM[b](64x2048) @ Wu   (bf16 MFMA, BK=64, swizzled LDS)
//   score[l]   = sum_u tanh(S1 + q[b,u]) * Wv[u]
//   attn       = softmax_l(score)   -> d_out
//   ctx[b,:]   = sum_l attn[l]*FM[b,l,:]  -> x_bf16[b, 0:2048]
// block 512 (8 waves); wave w owns u in [w*64, w*64+64)
__global__ __launch_bounds__(512) void k_attn(
    const float* __restrict__ fm, const u16* __restrict__ WuT,
    const float* __restrict__ q, const float* __restrict__ Wv,
    float* __restrict__ attn_out, u16* __restrict__ xbf){
  __shared__ __align__(16) u16 Al[64 * 64];     // 8 KB  [row][slot^(row&7)]
  __shared__ __align__(16) u16 Bl[512 * 64];    // 64 KB [n][slot^(n&7)]
  __shared__ float qv[512], wvv[512];
  __shared__ float scoreBuf[8][64];
  __shared__ float attn_s[64];

  int b = blockIdx.x;
  int tid = threadIdx.x, wid = tid >> 6, lane = tid & 63;
  qv[tid] = q[(size_t)b * 512 + tid];
  wvv[tid] = Wv[tid];
  const float* fmb = fm + (size_t)b * (64 * 2048);

  f32x4 acc[4][4];
#pragma unroll
  for (int i = 0; i < 4; i++)
#pragma unroll
    for (int j = 0; j < 4; j++) acc[i][j] = (f32x4){0.f, 0.f, 0.f, 0.f};

  int arow = tid >> 3, ac = tid & 7;
  int asl = ac ^ (arow & 7);

  for (int t = 0; t < 32; t++){
    int k0 = t << 6;
    __syncthreads();                       // previous compute done before overwrite
    // stage A: FM tile 64x64 f32 -> bf16 (reg-staged, swizzled ds_write)
    const float* ga = fmb + (size_t)arow * 2048 + k0 + ac * 8;
    float4 v0 = *(const float4*)ga;
    float4 v1 = *(const float4*)(ga + 4);
    union { u16 s[8]; uint4 q; } pk;
    pk.s[0] = f2bf(v0.x); pk.s[1] = f2bf(v0.y); pk.s[2] = f2bf(v0.z); pk.s[3] = f2bf(v0.w);
    pk.s[4] = f2bf(v1.x); pk.s[5] = f2bf(v1.y); pk.s[6] = f2bf(v1.z); pk.s[7] = f2bf(v1.w);
    *(uint4*)&Al[arow * 64 + asl * 8] = pk.q;
    // stage B: WuT tile 512x64 bf16 via global_load_lds (source pre-swizzled, LDS linear)
#pragma unroll
    for (int i = 0; i < 8; i++){
      int p = ((wid * 8 + i) << 6) + lane;      // chunk id 0..4095
      int n = p >> 3, sl = p & 7;
      int sl2 = sl ^ (n & 7);
      gload16(WuT + (size_t)n * 2048 + k0 + sl2 * 8,
              (char*)Bl + (size_t)(wid * 8 + i) * 1024);
    }
    __syncthreads();                       // drains vmcnt (gload_lds) + lgkm (ds_write)
#pragma unroll
    for (int kh = 0; kh < 2; kh++){
      short8 af[4], bfr[4];
#pragma unroll
      for (int mi = 0; mi < 4; mi++){
        int r = mi * 16 + (lane & 15);
        af[mi] = *(const short8*)&Al[r * 64 + (((kh << 2) + (lane >> 4)) ^ (r & 7)) * 8];
      }
#pragma unroll
      for (int ni = 0; ni < 4; ni++){
        int nr = wid * 64 + ni * 16 + (lane & 15);
        bfr[ni] = *(const short8*)&Bl[nr * 64 + (((kh << 2) + (lane >> 4)) ^ (nr & 7)) * 8];
      }
#pragma unroll
      for (int mi = 0; mi < 4; mi++)
#pragma unroll
        for (int ni = 0; ni < 4; ni++)
          acc[mi][ni] = mfma16(af[mi], bfr[ni], acc[mi][ni]);
    }
  }

  // epilogue: tanh + dot(Wv), lane-local partials for 16 (mi,j) rows
  float part[16];
#pragma unroll
  for (int mi = 0; mi < 4; mi++)
#pragma unroll
    for (int j = 0; j < 4; j++){
      float s = 0.f;
#pragma unroll
      for (int ni = 0; ni < 4; ni++){
        int u = wid * 64 + ni * 16 + (lane & 15);
        s += tanh_fast(acc[mi][ni][j] + qv[u]) * wvv[u];
      }
      part[mi * 4 + j] = s;
    }
#pragma unroll
  for (int i = 0; i < 16; i++){
    part[i] += __shfl_xor(part[i], 1);
    part[i] += __shfl_xor(part[i], 2);
    part[i] += __shfl_xor(part[i], 4);
    part[i] += __shfl_xor(part[i], 8);
  }
  if ((lane & 15) == 0){
    int g = lane >> 4;
#pragma unroll
    for (int mi = 0; mi < 4; mi++)
#pragma unroll
      for (int j = 0; j < 4; j++)
        scoreBuf[wid][mi * 16 + g * 4 + j] = part[mi * 4 + j];
  }
  __syncthreads();
  if (tid < 64){                            // wave 0: softmax over L=64
    float s = 0.f;
#pragma unroll
    for (int w = 0; w < 8; w++) s += scoreBuf[w][tid];
    float mx = s;
#pragma unroll
    for (int m = 32; m >= 1; m >>= 1) mx = fmaxf(mx, __shfl_xor(mx, m));
    float e = __expf(s - mx);
    float sum = e;
#pragma unroll
    for (int m = 32; m >= 1; m >>= 1) sum += __shfl_xor(sum, m);
    float a = e / sum;
    attn_s[tid] = a;
    attn_out[(size_t)b * 64 + tid] = a;
  }
  __syncthreads();
  // ctx: thread owns 4 consecutive d (float4)
  const float4* fmr = (const float4*)fmb;
  float4 cx = {0.f, 0.f, 0.f, 0.f};
  for (int l = 0; l < 64; l++){
    float a = attn_s[l];
    float4 v = fmr[l * 512 + tid];
    cx.x = fmaf(a, v.x, cx.x); cx.y = fmaf(a, v.y, cx.y);
    cx.z = fmaf(a, v.z, cx.z); cx.w = fmaf(a, v.w, cx.w);
  }
  uint2 o;
  o.x = (u32)f2bf(cx.x) | ((u32)f2bf(cx.y) << 16);
  o.y = (u32)f2bf(cx.z) | ((u32)f2bf(cx.w) << 16);
  *(uint2*)&xbf[(size_t)b * 2304 + tid * 4] = o;
}

// ---------------------------------------------------------------------------
// generic GEMM: C(MxN) = A(MxK bf16) @ Bt(NxK bf16)^T, epilogue scale/offset
// 128x128 tile, BK=64, 8 waves (2x4), double-buffered, gload_lds both operands
template<bool OBF>
__global__ __launch_bounds__(512) void k_gemm(
    const u16* __restrict__ A, const u16* __restrict__ Bt,
    const float* __restrict__ scale, const float* __restrict__ off,
    void* __restrict__ Cout, int K, int N){
  __shared__ __align__(16) u16 Alds[2][128 * 64];   // 16 KB each
  __shared__ __align__(16) u16 Blds[2][128 * 64];
  int n0 = blockIdx.x << 7, m0 = blockIdx.y << 7;
  int tid = threadIdx.x, wid = tid >> 6, lane = tid & 63;
  int wm = wid >> 2, wn = wid & 3;

  f32x4 acc[4][2];
#pragma unroll
  for (int i = 0; i < 4; i++)
#pragma unroll
    for (int j = 0; j < 2; j++) acc[i][j] = (f32x4){0.f, 0.f, 0.f, 0.f};

  auto stage = [&](int s, int k0){
#pragma unroll
    for (int i = 0; i < 2; i++){
      int p = ((wid * 2 + i) << 6) + lane;      // chunk 0..1023
      int row = p >> 3, sl = p & 7, sl2 = sl ^ (row & 7);
      gload16(A  + (size_t)(m0 + row) * K + k0 + sl2 * 8,
              (char*)Alds[s] + (size_t)(wid * 2 + i) * 1024);
      gload16(Bt + (size_t)(n0 + row) * K + k0 + sl2 * 8,
              (char*)Blds[s] + (size_t)(wid * 2 + i) * 1024);
    }
  };

  int nk = K >> 6;
  stage(0, 0);
  __syncthreads();
  int cur = 0;
  for (int t = 0; t < nk; t++){
    if (t + 1 < nk) stage(cur ^ 1, (t + 1) << 6);
#pragma unroll
    for (int kh = 0; kh < 2; kh++){
      short8 af[4], bfr[2];
#pragma unroll
      for (int mi = 0; mi < 4; mi++){
        int r = wm * 64 + mi * 16 + (lane & 15);
        af[mi] = *(const short8*)&Alds[cur][r * 64 + (((kh << 2) + (lane >> 4)) ^ (r & 7)) * 8];
      }
#pragma unroll
      for (int ni = 0; ni < 2; ni++){
        int r = wn * 32 + ni * 16 + (lane & 15);
        bfr[ni] = *(const short8*)&Blds[cur][r * 64 + (((kh << 2) + (lane >> 4)) ^ (r & 7)) * 8];
      }
#pragma unroll
      for (int mi = 0; mi < 4; mi++)
#pragma unroll
        for (int ni = 0; ni < 2; ni++)
          acc[mi][ni] = mfma16(af[mi], bfr[ni], acc[mi][ni]);
    }
    __syncthreads();
    cur ^= 1;
  }
#pragma unroll
  for (int ni = 0; ni < 2; ni++){
    int n = n0 + wn * 32 + ni * 16 + (lane & 15);
    float sc = scale ? scale[n] : 1.f;
    float of = off ? off[n] : 0.f;
#pragma unroll
    for (int mi = 0; mi < 4; mi++)
#pragma unroll
      for (int j = 0; j < 4; j++){
        int m = m0 + wm * 64 + mi * 16 + (lane >> 4) * 4 + j;
        float v = acc[mi][ni][j] * sc + of;
        if (OBF) ((u16*)Cout)[(size_t)m * N + n] = f2bf(v);
        else     ((float*)Cout)[(size_t)m * N + n] = v;
      }
  }
}

// ---------------------------------------------------------------------------
// GRU gates (elementwise): h = (1-z)*hh ; grid 1024 (b), block 512 (u)
__global__ __launch_bounds__(512) void k_gates(
    const float* __restrict__ xg, const float* __restrict__ gru_b,
    float* __restrict__ hout, u16* __restrict__ hbf){
  int b = blockIdx.x, u = threadIdx.x;
  const float* rg = gru_b + 1536;
  size_t base = (size_t)b * 1536;
  float z  = sigmoidf_(xg[base + u]        + rg[u]);
  float r  = sigmoidf_(xg[base + 512 + u]  + rg[512 + u]);
  float hh = tanh_fast(xg[base + 1024 + u] + r * rg[1024 + u]);
  float h = (1.f - z) * hh;
  hout[(size_t)b * 512 + u] = h;
  hbf[(size_t)b * 512 + u] = f2bf(h);
}

// ---------------------------------------------------------------------------
extern "C" void kernel_launch(void* const* d_in, const int* in_sizes, int n_in,
                              void* d_out, int out_size, void* d_ws, size_t ws_size,
                              hipStream_t stream){
  const int*   tok   = (const int*)  d_in[0];
  const float* fm    = (const float*)d_in[1];
  const float* ps    = (const float*)d_in[2];
  const float* emb   = (const float*)d_in[3];
  const float* Wu    = (const float*)d_in[4];
  const float* bu    = (const float*)d_in[5];
  const float* Ww    = (const float*)d_in[6];
  const float* bw    = (const float*)d_in[7];
  const float* Wv    = (const float*)d_in[8];
  // d_in[9] = bv: softmax-invariant, unused. d_in[11] = gru_rk: dead in reference.
  const float* gru_k = (const float*)d_in[10];
  const float* gru_b = (const float*)d_in[12];
  const float* W1    = (const float*)d_in[13];
  const float* b1    = (const float*)d_in[14];
  const float* gamma = (const float*)d_in[15];
  const float* beta  = (const float*)d_in[16];
  const float* mmean = (const float*)d_in[17];
  const float* mvar  = (const float*)d_in[18];
  const float* W2    = (const float*)d_in[19];
  const float* b2    = (const float*)d_in[20];

  float* logits = (float*)d_out;                     // 1024 x 32000
  float* hout   = (float*)d_out + 32768000;          // 1024 x 512
  float* attn   = (float*)d_out + 33292288;          // 1024 x 64

  char* ws = (char*)d_ws;
  u16*   WuT = (u16*)  (ws + 0);          // 512  x 2048 bf16   2,097,152 B
  u16*   gkT = (u16*)  (ws + 2097152);    // 1536 x 2304 bf16   7,077,888 B
  u16*   W2T = (u16*)  (ws + 9175040);    // 32000x 512  bf16  32,768,000 B
  u16*   W1T = (u16*)  (ws + 41943040);   // 512  x 512  bf16     524,288 B
  float* qws = (float*)(ws + 42467328);   // 1024 x 512  f32    2,097,152 B
  u16*   xbf = (u16*)  (ws + 44564480);   // 1024 x 2304 bf16   4,718,592 B
  float* xg  = (float*)(ws + 49283072);   // 1024 x 1536 f32    6,291,456 B
  u16*   hbf = (u16*)  (ws + 55574528);   // 1024 x 512  bf16   1,048,576 B
  u16*   ybf = (u16*)  (ws + 56623104);   // 1024 x 512  bf16   1,048,576 B
  float* bns = (float*)(ws + 57671680);   // 512 f32
  float* bno = (float*)(ws + 57673728);   // 512 f32

  // weight transposes + bf16 conversion
  k_transpose_cvt<<<dim3(32, 8),  256, 0, stream>>>(Wu,    WuT, 2048, 512);
  k_transpose_cvt<<<dim3(36, 24), 256, 0, stream>>>(gru_k, gkT, 2304, 1536);
  k_transpose_cvt<<<dim3(8, 500), 256, 0, stream>>>(W2,    W2T, 512,  32000);
  k_transpose_cvt<<<dim3(8, 8),   256, 0, stream>>>(W1,    W1T, 512,  512);
  // small f32 preps
  k_q<<<128, 512, 0, stream>>>(ps, Ww, bw, bu, qws);
  k_gather<<<1024, 256, 0, stream>>>(tok, emb, xbf);
  k_bnprep<<<1, 512, 0, stream>>>(gamma, beta, mmean, mvar, b1, bns, bno);
  // fused attention (score GEMM + softmax + ctx)
  k_attn<<<1024, 512, 0, stream>>>(fm, WuT, qws, Wv, attn, xbf);
  // xg = x @ gru_k + gru_b[0]
  k_gemm<false><<<dim3(12, 8), 512, 0, stream>>>(xbf, gkT, nullptr, gru_b, xg, 2304, 1536);
  // gates -> h
  k_gates<<<1024, 512, 0, stream>>>(xg, gru_b, hout, hbf);
  // y = BN(h @ W1 + b1) -> bf16
  k_gemm<true><<<dim3(4, 8), 512, 0, stream>>>(hbf, W1T, bns, bno, ybf, 512, 512);
  // logits = y @ W2 + b2
  k_gemm<false><<<dim3(250, 8), 512, 0, stream>>>(ybf, W2T, nullptr, b2, logits, 512, 32000);
}